// Round 4
// baseline (788.373 us; speedup 1.0000x reference)
//
#include <hip/hip_runtime.h>
#include <math.h>

// Problem constants
static constexpr int B  = 32;
static constexpr int S  = 32;
static constexpr int T  = 31;     // S - 1
static constexpr int H  = 256;
static constexpr int H3 = 768;    // 3*H
static constexpr int V  = 12000;
static constexpr int BLK = 768;   // k_rec block size (12 waves)

typedef float f2 __attribute__((ext_vector_type(2)));

// ---------------------------------------------------------------------------
// K_pre: EW tables.  EW_x[r][o] = (embed[r] @ xW + xb)[o]  for r in 0..31.
// Only embed rows 0..31 are ever used by the recurrence (la = a*acc <= 31).
// Table order in ws: x=0 -> aW, 1 -> sW, 2 -> bW, 3 -> rW.
// ---------------------------------------------------------------------------
__global__ __launch_bounds__(768) void k_ew(
    const float* __restrict__ embed,
    const float* __restrict__ aW, const float* __restrict__ ab,
    const float* __restrict__ sW, const float* __restrict__ sb,
    const float* __restrict__ bW, const float* __restrict__ bb,
    const float* __restrict__ rW, const float* __restrict__ rb,
    float* __restrict__ ew)
{
    const int r = blockIdx.x;   // embed row 0..31
    const int x = blockIdx.y;   // table 0..3
    const int o = threadIdx.x;  // 0..767
    const float* W; const float* bias;
    if      (x == 0) { W = aW; bias = ab; }
    else if (x == 1) { W = sW; bias = sb; }
    else if (x == 2) { W = bW; bias = bb; }
    else             { W = rW; bias = rb; }
    const float* e = embed + (size_t)r * H;
    float acc = bias[o];
    #pragma unroll 4
    for (int i = 0; i < H; ++i) acc += e[i] * W[(size_t)i * H3 + o];
    ew[((size_t)x * 32 + r) * H3 + o] = acc;
}

// ---------------------------------------------------------------------------
// K0: integer control simulation.  One wave; lane b simulates element b.
// Emits per (b,t): la, successful-pop count, and flags
//   bit0 = reduce succeeded (run GRU over pops, push rfinal)
//   bit1 = NT push, bit2 = GEN stack push, bit3 = GEN buffer push
// Handles the batch-global red_mult zeroing exactly (any_red && total_pops==0
// kills the whole batch; per-element failed reduce kills that element).
// NOTE step ordering matches the reference: is_nt/is_gen derive from la
// computed BEFORE the red_mult acc update, so a batch-kill step still
// performs that step's NT/GEN pushes.
// ---------------------------------------------------------------------------
__global__ __launch_bounds__(64) void k_ctl(
    const int* __restrict__ actions,
    int* __restrict__ la_o, int* __restrict__ pops_o, int* __restrict__ flags_o)
{
    const int lane = threadIdx.x;          // 0..63; lanes >= 32 are dummies
    const bool valid = (lane < B);
    int st = -1, bt = 0, acc = 1;
    unsigned tags = 0u;                    // bit k = tag of stack slot k

    for (int t = 0; t < T; ++t) {
        const int a  = valid ? actions[lane * S + t] : 0;
        const int la = acc ? a : 0;
        const int is_red = (la == 2);
        const int is_nt  = (la > 2 && la < 16);
        const int is_gen = (la >= 16);

        int pops = 0, racc = 1, j = -1;
        if (is_red) {
            if (st < 0) { pops = 0; racc = 0; }
            else {
                const unsigned below =
                    tags & (st >= 31 ? 0xFFFFFFFFu : ((1u << (st + 1)) - 1u));
                if (below) { j = 31 - __builtin_clz(below); pops = st - j + 1; racc = 1; }
                else       { pops = st + 1; racc = 0; }  // drains whole stack
            }
        }
        // batch-global coupling (uniform re-convergent point)
        const unsigned long long red_ballot = __ballot(is_red);
        const int any_red = (red_ballot != 0ull);
        int tot = pops;
        for (int m = 32; m >= 1; m >>= 1) tot += __shfl_xor(tot, m, 64);

        int redgo = 0;
        if (is_red) {
            if (racc) {                    // pop st..j, push rfinal (tag 0) at j
                st = j;
                tags &= (j == 0 ? 0u : ((1u << j) - 1u));
                redgo = 1;
            } else {
                st -= pops;                // failed reduce drains the stack
                tags = 0u;
            }
        }
        const int racc_local = is_red ? racc : 1;
        const int red_mult   = any_red ? ((tot == 0) ? 0 : racc_local) : 1;
        acc = acc * red_mult;

        int ntp = 0, sp = 0, bp = 0;
        if (is_nt) {
            if (st + 1 < S) { st++; tags |= (1u << st); ntp = 1; }
            else acc = 0;
        }
        if (is_gen) {
            if (st + 1 < S) {
                st++; tags &= ~(1u << st); sp = 1;
                if (bt + 1 < S) { bt++; bp = 1; } else acc = 0;
            } else acc = 0;
        }
        if (valid) {
            la_o[lane * T + t]    = la;
            pops_o[lane * T + t]  = pops;
            flags_o[lane * T + t] = redgo | (ntp << 1) | (sp << 2) | (bp << 3);
        }
    }
}

// ---------------------------------------------------------------------------
// GRU cell, 768 threads.  hu = h@U: thread (half, j) computes column pair
// (2j, 2j+1) over rows half*128..+127 with an f2 accumulator (dwordx2 U loads;
// compiler can pack v_pk_fma_f32).  Gates on threads 0..255.
// Column layout: [z | r | n].  hin/hout/part are LDS; xw may be LDS or global.
// hzero==1 means h == 0 (hin never dereferenced).  Safe in-place (hin==hout):
// all matvec reads of hin precede the first barrier, writes follow it.
// ---------------------------------------------------------------------------
__device__ __forceinline__ void cell768(
    int tid, const float* hin, int hzero, const float* xw,
    const float* __restrict__ U, float* hout, float* part)
{
    const int half = (tid >= 384) ? 1 : 0;
    const int j    = tid - half * 384;        // 0..383 -> cols (2j, 2j+1)
    f2 acc = {0.f, 0.f};
    if (!hzero) {
        const int i0 = half << 7;             // 0 or 128
        const float* Ub = U + (size_t)i0 * H3 + 2 * j;
        #pragma unroll 4
        for (int i = 0; i < 128; i += 4) {
            const float4 hv = *(const float4*)(hin + i0 + i);
            const float* Ur = Ub + (size_t)i * H3;
            const f2 u0 = *(const f2*)(Ur);
            const f2 u1 = *(const f2*)(Ur + H3);
            const f2 u2 = *(const f2*)(Ur + 2 * H3);
            const f2 u3 = *(const f2*)(Ur + 3 * H3);
            acc += hv.x * u0;
            acc += hv.y * u1;
            acc += hv.z * u2;
            acc += hv.w * u3;
        }
    }
    *(f2*)(part + half * H3 + 2 * j) = acc;
    __syncthreads();
    if (tid < 256) {
        const int t = tid;
        const float huz = part[t]       + part[H3 + t];
        const float hur = part[256 + t] + part[H3 + 256 + t];
        const float hun = part[512 + t] + part[H3 + 512 + t];
        const float z = 1.f / (1.f + expf(-(xw[t]       + huz)));
        const float r = 1.f / (1.f + expf(-(xw[256 + t] + hur)));
        const float n = tanhf(xw[512 + t] + r * hun);
        const float hold = hzero ? 0.f : hin[t];
        hout[t] = (1.f - z) * hold + z * n;
    }
    __syncthreads();
}

// out[o] = bias[o] + sum_i hin[i]*W[i][o]   (projection of rfinal; no gating)
// 768 threads -> one output column each.
__device__ __forceinline__ void proj768(
    int tid, const float* hin, const float* __restrict__ W,
    const float* __restrict__ bias, float* out)
{
    const int o = tid;
    float acc = bias[o];
    #pragma unroll 4
    for (int i = 0; i < H; i += 4) {
        const float4 hv = *(const float4*)(hin + i);
        const float* Wr = W + (size_t)i * H3 + o;
        acc += hv.x * Wr[0] + hv.y * Wr[H3] + hv.z * Wr[2*H3] + hv.w * Wr[3*H3];
    }
    out[o] = acc;
}

// ---------------------------------------------------------------------------
// K1: per-element float recurrence.  One workgroup per batch element.
// Maintains prefix-hidden states PH for stack & buffer encodes in LDS
// (incremental encode: only the changed suffix is recomputed — exact).
// Writes concat = [stk_e | ah | buf_e] per (b,t) to ws.
// ---------------------------------------------------------------------------
__global__ __launch_bounds__(768) void k_rec(
    const float* __restrict__ ew,        // EW tables (a,s,b,r)
    float* __restrict__ xwr_ws,          // [B][S][H3] cached x@rW+rb per stack slot
    float* __restrict__ concat_ws,       // [B*T][H3]
    const int* __restrict__ la_arr, const int* __restrict__ pops_arr,
    const int* __restrict__ flags_arr,
    const float* __restrict__ aU, const float* __restrict__ sU,
    const float* __restrict__ bU, const float* __restrict__ rU,
    const float* __restrict__ sWm, const float* __restrict__ sbv,
    const float* __restrict__ rWm, const float* __restrict__ rbv)
{
    const int b   = blockIdx.x;
    const int tid = threadIdx.x;

    __shared__ alignas(16) float PHs[S][H];   // 32 KB  stack prefix hiddens
    __shared__ alignas(16) float PHb[S][H];   // 32 KB  buffer prefix hiddens
    __shared__ alignas(16) float hred[H];
    __shared__ alignas(16) float ahh[H];
    __shared__ alignas(16) float ZERO[H];
    __shared__ alignas(16) float xwtmp[H3];
    __shared__ alignas(16) float part[2 * H3];

    const float* EW_a = ew;
    const float* EW_s = ew + 32 * H3;
    const float* EW_b = ew + 2 * 32 * H3;
    const float* EW_r = ew + 3 * 32 * H3;
    float* xwr = xwr_ws + (size_t)b * S * H3;

    for (int i = tid; i < H; i += BLK) { ahh[i] = 0.f; ZERO[i] = 0.f; }
    __syncthreads();

    // buffer init: push embed[START_ID=1]  ->  PHb[0] = gru(0, EW_b[1])
    cell768(tid, ZERO, 1, EW_b + 1 * H3, bU, PHb[0], part);
    int st = -1, bt = 0;

    for (int t = 0; t < T; ++t) {
        const int la    = la_arr[b * T + t];
        const int pops  = pops_arr[b * T + t];
        const int flags = flags_arr[b * T + t];
        const int redgo = flags & 1, ntp = (flags >> 1) & 1;
        const int sp    = (flags >> 2) & 1, bp = (flags >> 3) & 1;

        if (redgo) {
            // GRU over popped slots (top-down), slots st .. st-pops+1
            for (int p = 0; p < pops; ++p) {
                const int slot = st - p;
                cell768(tid, hred, (p == 0) ? 1 : 0, xwr + (size_t)slot * H3,
                        rU, hred, part);
            }
            const int jj = st - pops + 1;           // push position
            proj768(tid, hred, sWm, sbv, xwtmp);                 // rfinal@sW+sb
            proj768(tid, hred, rWm, rbv, xwr + (size_t)jj * H3); // rfinal@rW+rb
            __syncthreads();
            cell768(tid, (jj == 0) ? ZERO : PHs[jj - 1], (jj == 0) ? 1 : 0,
                    xwtmp, sU, PHs[jj], part);
            st = jj;
        } else {
            st -= pops;   // failed reduce drained pops (or pops==0)
        }
        if (ntp | sp) {   // NT or GEN stack push of embed[la]
            const int slot = st + 1;
            xwr[(size_t)slot * H3 + tid] = EW_r[(size_t)la * H3 + tid];
            cell768(tid, (st < 0) ? ZERO : PHs[st], (st < 0) ? 1 : 0,
                    EW_s + (size_t)la * H3, sU, PHs[slot], part);
            st = slot;
        }
        if (bp) {         // GEN buffer push
            cell768(tid, PHb[bt], 0, EW_b + (size_t)la * H3, bU, PHb[bt + 1], part);
            bt = bt + 1;
        }
        // action GRU (always runs; in-place is safe in cell768)
        cell768(tid, ahh, 0, EW_a + (size_t)la * H3, aU, ahh, part);

        // concat = [stk_e | ah | buf_e]
        float* cc = concat_ws + (size_t)(b * T + t) * H3;
        if (tid < H) {
            const int o = tid;
            cc[o]       = (st >= 0) ? PHs[st][o] : 0.f;
            cc[256 + o] = ahh[o];
            cc[512 + o] = PHb[bt][o];
        }
        __syncthreads();
    }
}

// ---------------------------------------------------------------------------
// K2: att = tanh(concat @ Wc + bc)     [992,768]@[768,256]
// ---------------------------------------------------------------------------
__global__ __launch_bounds__(256) void k_att(
    const float* __restrict__ concat_ws,
    const float* __restrict__ Wc, const float* __restrict__ bc,
    float* __restrict__ att_ws)
{
    const int rb  = blockIdx.x;       // 248 blocks x 4 rows
    const int tid = threadIdx.x;      // output column
    __shared__ alignas(16) float cL[4 * H3];   // 12 KB
    const int row0 = rb * 4;
    for (int k = tid; k < 4 * H3; k += 256)
        cL[k] = concat_ws[(size_t)row0 * H3 + k];
    __syncthreads();
    float acc0 = bc[tid], acc1 = bc[tid], acc2 = bc[tid], acc3 = bc[tid];
    for (int i = 0; i < H3; i += 4) {
        const float w0 = Wc[(size_t)(i + 0) * H + tid];
        const float w1 = Wc[(size_t)(i + 1) * H + tid];
        const float w2 = Wc[(size_t)(i + 2) * H + tid];
        const float w3 = Wc[(size_t)(i + 3) * H + tid];
        float4 c;
        c = *(const float4*)&cL[0 * H3 + i]; acc0 += c.x*w0 + c.y*w1 + c.z*w2 + c.w*w3;
        c = *(const float4*)&cL[1 * H3 + i]; acc1 += c.x*w0 + c.y*w1 + c.z*w2 + c.w*w3;
        c = *(const float4*)&cL[2 * H3 + i]; acc2 += c.x*w0 + c.y*w1 + c.z*w2 + c.w*w3;
        c = *(const float4*)&cL[3 * H3 + i]; acc3 += c.x*w0 + c.y*w1 + c.z*w2 + c.w*w3;
    }
    att_ws[(size_t)(row0 + 0) * H + tid] = tanhf(acc0);
    att_ws[(size_t)(row0 + 1) * H + tid] = tanhf(acc1);
    att_ws[(size_t)(row0 + 2) * H + tid] = tanhf(acc2);
    att_ws[(size_t)(row0 + 3) * H + tid] = tanhf(acc3);
}

// ---------------------------------------------------------------------------
// K3: logits = att @ Wp + bp    [992,256]@[256,12000]
// Row tiles of 62, col tiles of 256.  grid (16, 47).
// ---------------------------------------------------------------------------
__global__ __launch_bounds__(256) void k_logits(
    const float* __restrict__ att_ws,
    const float* __restrict__ Wp, const float* __restrict__ bp,
    float* __restrict__ out_logits)
{
    const int rt = blockIdx.x, ct = blockIdx.y;
    const int tid = threadIdx.x;
    __shared__ alignas(16) float aL[62 * H];   // 63.5 KB
    const int row0 = rt * 62;
    for (int k = tid; k < 62 * H; k += 256)
        aL[k] = att_ws[(size_t)row0 * H + k];
    __syncthreads();
    const int c = ct * 256 + tid;
    if (c >= V) return;
    float acc[62];
    #pragma unroll
    for (int r = 0; r < 62; ++r) acc[r] = 0.f;
    for (int i = 0; i < H; i += 4) {
        const float w0 = Wp[(size_t)(i + 0) * V + c];
        const float w1 = Wp[(size_t)(i + 1) * V + c];
        const float w2 = Wp[(size_t)(i + 2) * V + c];
        const float w3 = Wp[(size_t)(i + 3) * V + c];
        #pragma unroll
        for (int r = 0; r < 62; ++r) {
            const float4 av = *(const float4*)&aL[r * H + i];
            acc[r] += av.x * w0 + av.y * w1 + av.z * w2 + av.w * w3;
        }
    }
    const float bpv = bp[c];
    #pragma unroll
    for (int r = 0; r < 62; ++r)
        out_logits[(size_t)(row0 + r) * V + c] = acc[r] + bpv;
}

// ---------------------------------------------------------------------------
// K4: preds = argmax(logits, axis=-1), first-occurrence semantics.
// ---------------------------------------------------------------------------
__global__ __launch_bounds__(256) void k_argmax(
    const float* __restrict__ logits, float* __restrict__ preds)
{
    const int row = blockIdx.x;     // 0..991  (= b*T + t)
    const int tid = threadIdx.x;
    const float* lg = logits + (size_t)row * V;
    float bv = -INFINITY; int bi = V;
    for (int c = tid; c < V; c += 256) {
        const float v = lg[c];
        if (v > bv) { bv = v; bi = c; }   // increasing c -> keeps first max
    }
    __shared__ float sv[256];
    __shared__ int   si[256];
    sv[tid] = bv; si[tid] = bi;
    __syncthreads();
    for (int off = 128; off > 0; off >>= 1) {
        if (tid < off) {
            const float v2 = sv[tid + off]; const int i2 = si[tid + off];
            if (v2 > sv[tid] || (v2 == sv[tid] && i2 < si[tid])) {
                sv[tid] = v2; si[tid] = i2;
            }
        }
        __syncthreads();
    }
    if (tid == 0) preds[row] = (float)si[0];
}

// ---------------------------------------------------------------------------
extern "C" void kernel_launch(void* const* d_in, const int* in_sizes, int n_in,
                              void* d_out, int out_size, void* d_ws, size_t ws_size,
                              hipStream_t stream)
{
    (void)in_sizes; (void)n_in; (void)out_size; (void)ws_size;
    const int*   actions = (const int*)  d_in[0];
    const float* embed   = (const float*)d_in[1];
    const float* aW = (const float*)d_in[2];
    const float* aU = (const float*)d_in[3];
    const float* ab = (const float*)d_in[4];
    const float* bW = (const float*)d_in[5];
    const float* bU = (const float*)d_in[6];
    const float* bb = (const float*)d_in[7];
    const float* sW = (const float*)d_in[8];
    const float* sU = (const float*)d_in[9];
    const float* sb = (const float*)d_in[10];
    const float* rW = (const float*)d_in[11];
    const float* rU = (const float*)d_in[12];
    const float* rb = (const float*)d_in[13];
    const float* Wc = (const float*)d_in[14];
    const float* bc = (const float*)d_in[15];
    const float* Wp = (const float*)d_in[16];
    const float* bp = (const float*)d_in[17];

    // workspace layout (floats)
    float* wsf  = (float*)d_ws;
    float* ew   = wsf;                    //  4*32*768           =   98304
    float* xwr  = wsf + 98304;            //  32*32*768          =  786432
    float* conc = wsf + 884736;           //  992*768            =  761856
    float* att  = wsf + 1646784;          //  992*256            =  253952
    int*   ctli = (int*)(wsf + 1900736);  //  3*992 ints
    int* la_a    = ctli;
    int* pops_a  = ctli + B * T;
    int* flags_a = ctli + 2 * B * T;

    float* outf   = (float*)d_out;
    float* preds  = outf;                 // [B,T] as float
    float* logits = outf + B * T;         // [B,T,V]

    hipLaunchKernelGGL(k_ew, dim3(32, 4), dim3(768), 0, stream,
                       embed, aW, ab, sW, sb, bW, bb, rW, rb, ew);
    hipLaunchKernelGGL(k_ctl, dim3(1), dim3(64), 0, stream,
                       actions, la_a, pops_a, flags_a);
    hipLaunchKernelGGL(k_rec, dim3(B), dim3(BLK), 0, stream,
                       ew, xwr, conc, la_a, pops_a, flags_a,
                       aU, sU, bU, rU, sW, sb, rW, rb);
    hipLaunchKernelGGL(k_att, dim3(248), dim3(256), 0, stream,
                       conc, Wc, bc, att);
    hipLaunchKernelGGL(k_logits, dim3(16, 47), dim3(256), 0, stream,
                       att, Wp, bp, logits);
    hipLaunchKernelGGL(k_argmax, dim3(B * T), dim3(256), 0, stream,
                       logits, preds);
}